// Round 1
// 270.690 us; speedup vs baseline: 1.1027x; 1.1027x over previous
//
#include <hip/hip_runtime.h>
#include <stdint.h>

#define B_   8
#define N_   512
#define CE_  16
#define BN_  (B_*N_)   // 4096
#define Q_   8         // i-partition partials (8 blocks/CU for latency hiding)

typedef __attribute__((ext_vector_type(8))) short bf16x8;
typedef __attribute__((ext_vector_type(4))) short bf16x4;
typedef __attribute__((ext_vector_type(4))) float f32x4;
typedef __attribute__((ext_vector_type(2))) float f32x2;
typedef __attribute__((ext_vector_type(4))) int   i32x4;
typedef __attribute__((ext_vector_type(2))) int   i32x2;

// exact-K MFMA (K=16, no padded half) if the legacy 1k builtin exists on this
// toolchain; otherwise fall back to the verified 16x16x32 zero-padded path.
#if defined(__has_builtin)
#  if __has_builtin(__builtin_amdgcn_mfma_f32_16x16x16bf16_1k)
#    define HAVE_MFMA16 1
#  endif
#endif
#ifndef HAVE_MFMA16
#  define HAVE_MFMA16 0
#endif

union PackA8 { i32x4 i; bf16x8 h; };
union PackA4 { i32x2 i; bf16x4 h; };
union V4     { f32x4 v; f32x2 h[2]; };

__device__ __forceinline__ unsigned short f2bf_rne(float f) {
  unsigned u = __float_as_uint(f);
  u += 0x7FFFu + ((u >> 16) & 1u);
  return (unsigned short)(u >> 16);
}

// packed fp32 (VOP3P, CDNA2+): 2 scalar ops per instruction slot (worst case
// cycle-neutral if pk f32 runs at half rate on gfx950; best case -50% slots)
__device__ __forceinline__ f32x2 pk_fma(f32x2 a, f32x2 b, f32x2 c) {
  f32x2 d;
  asm("v_pk_fma_f32 %0, %1, %2, %3" : "=v"(d) : "v"(a), "v"(b), "v"(c));
  return d;
}
__device__ __forceinline__ f32x2 pk_add2(f32x2 a, f32x2 b) {
  f32x2 d;
  asm("v_pk_add_f32 %0, %1, %2" : "=v"(d) : "v"(a), "v"(b));
  return d;
}

// ---------------- K1: row precompute (m1, m2, base) + Wc/bc + WeT pack ----------------
__global__ __launch_bounds__(256) void k1_pre(
    const float* __restrict__ x,
    const float* __restrict__ W1,  const float* __restrict__ b1,
    const float* __restrict__ W2,  const float* __restrict__ b2,
    const float* __restrict__ Wn,  const float* __restrict__ bn,
    const float* __restrict__ Wo1, const float* __restrict__ bo1,
    const float* __restrict__ Wo2, const float* __restrict__ bo2,
    const float* __restrict__ We,
    float* __restrict__ m1, float* __restrict__ m2, float* __restrict__ base,
    float* __restrict__ Wc, float* __restrict__ bc, unsigned* __restrict__ wePack)
{
  const int tid = threadIdx.x;
  const int bx  = blockIdx.x;
  if (bx >= BN_/4) {            // 4 tail blocks: Wc = Wo2@Wn split 16 rows each
    const int q4 = bx - BN_/4;  // (was 1 block = 4-6 us serial tail; now ~1.5 us)
    for (int idx = tid; idx < 16*64; idx += 256) {
      const int k = q4*16 + (idx >> 6), m = idx & 63;
      float acc = 0.f;
      #pragma unroll 8
      for (int t = 0; t < 64; ++t) acc += Wo2[k*64 + t] * Wn[t*64 + m];
      Wc[k*64 + m] = acc;
    }
    if (q4 == 0) {
      if (tid < 64) {
        float acc = 0.f;
        for (int t = 0; t < 64; ++t) acc += Wo2[tid*64 + t] * bn[t];
        bc[tid] = acc;
      }
      // pre-pack We^T into the exact per-lane MFMA B-fragment layout so k2's
      // setup is 4 vector loads instead of ~140 f2bf/pack instructions.
      const int c = tid >> 6, lane = tid & 63, col = lane & 15, quad = lane >> 4;
#if HAVE_MFMA16
      const float* wr = We + (c*16 + col)*CE_ + quad*4;
      wePack[tid*2+0] = ((unsigned)f2bf_rne(wr[1]) << 16) | f2bf_rne(wr[0]);
      wePack[tid*2+1] = ((unsigned)f2bf_rne(wr[3]) << 16) | f2bf_rne(wr[2]);
#else
      unsigned p0=0, p1=0, p2=0, p3=0;
      if (quad < 2) {           // B rows k>=16 stay ZERO (garbage-A trick)
        const float* wr = We + (c*16 + col)*CE_ + quad*8;
        p0 = ((unsigned)f2bf_rne(wr[1]) << 16) | f2bf_rne(wr[0]);
        p1 = ((unsigned)f2bf_rne(wr[3]) << 16) | f2bf_rne(wr[2]);
        p2 = ((unsigned)f2bf_rne(wr[5]) << 16) | f2bf_rne(wr[4]);
        p3 = ((unsigned)f2bf_rne(wr[7]) << 16) | f2bf_rne(wr[6]);
      }
      wePack[tid*4+0]=p0; wePack[tid*4+1]=p1; wePack[tid*4+2]=p2; wePack[tid*4+3]=p3;
#endif
    }
    return;
  }
  const int r = tid >> 6, m = tid & 63;
  const int row = bx*4 + r;
  __shared__ float xs[4][64];
  xs[r][m] = x[(size_t)row*64 + m];
  __syncthreads();
  const float* xr = xs[r];
  float a1 = b1[m], a2 = b2[m], a3 = bo1[m] + bo2[m];
  const float* w1r = W1  + m*64;
  const float* w2r = W2  + m*64;
  const float* w3r = Wo1 + m*64;
  #pragma unroll 8
  for (int c = 0; c < 64; ++c) {
    const float xv = xr[c];
    a1 += xv * w1r[c];
    a2 += xv * w2r[c];
    a3 += xv * w3r[c];
  }
  m1[(size_t)row*64 + m]   = a1;
  m2[(size_t)row*64 + m]   = a2;
  base[(size_t)row*64 + m] = a3;
}

// ---------------- K2: dense edge projection + relu + masked i-reduction ----------------
// block = 4 waves; block <-> (b, j-tile of 16, i-eighth); wave covers 16 i's.
// HAVE_MFMA16: exact K=16 MFMA, every lane loads a distinct f32x4 (no mirror
// duplication, 2 perms not 4). Fallback: verified 16x16x32 K-padded path.
// A[m=lane&15][k=quad*KW+j], C/D: col=lane&15, row=quad*4+reg (verified).
__global__ __launch_bounds__(256) void k2_main(
    const float* __restrict__ edge, const float* __restrict__ adj,
    const unsigned* __restrict__ wePack, const float* __restrict__ be,
    const float* __restrict__ m1,   const float* __restrict__ m2,
    float* __restrict__ pS, float* __restrict__ pdeg)
{
  const int tid  = threadIdx.x;
  const int lane = tid & 63;
  const int wid  = tid >> 6;
  const int col  = lane & 15;
  const int quad = lane >> 4;

  const int blk = blockIdx.x;       // 0..2047
  const int q   = blk & 7;          // i-eighth
  const int grp = blk >> 3;         // 0..255
  const int b   = grp >> 5;
  const int j0  = (grp & 31) << 4;
  const int i0  = q*64 + wid*16;

  // B fragments: one vector load per c from the pre-packed layout
#if HAVE_MFMA16
  bf16x4 bfr[4];
  { const i32x2* wp = (const i32x2*)wePack;
    #pragma unroll
    for (int c = 0; c < 4; ++c) { PackA4 u; u.i = wp[c*64 + lane]; bfr[c] = u.h; } }
#else
  bf16x8 bfr[4];
  { const i32x4* wp = (const i32x4*)wePack;
    #pragma unroll
    for (int c = 0; c < 4; ++c) { PackA8 u; u.i = wp[c*64 + lane]; bfr[c] = u.h; } }
#endif

  // m1 fragment (+be), laid out to match C rows j0+quad*4+reg
  f32x4 m1f[4];
  #pragma unroll
  for (int c = 0; c < 4; ++c) {
    const float bev = be[c*16 + col];
    const float* mp = m1 + (size_t)(b*N_ + j0 + quad*4)*64 + c*16 + col;
    m1f[c].x = mp[0]   + bev;
    m1f[c].y = mp[64]  + bev;
    m1f[c].z = mp[128] + bev;
    m1f[c].w = mp[192] + bev;
  }

  const f32x2 z2 = {0.f, 0.f};
  f32x2 S2[4][2];
  #pragma unroll
  for (int c = 0; c < 4; ++c) { S2[c][0] = z2; S2[c][1] = z2; }
  f32x2 dg0 = z2, dg1 = z2;

#if HAVE_MFMA16
  const float* ep = edge + ((size_t)(b*N_ + i0)*N_ + (j0 + col))*CE_ + quad*4;
#else
  const float* ep = edge + ((size_t)(b*N_ + i0)*N_ + (j0 + col))*CE_ + (quad & 1)*8;
#endif
  const float* ap  = adj + (size_t)(b*N_ + i0)*N_ + j0 + quad*4;
  const float* m2p = m2  + (size_t)(b*N_ + i0)*64 + col;

  for (int it = 0; it < 16; ++it) {
#if HAVE_MFMA16
    const f32x4 e0 = *(const f32x4*)ep;
    PackA4 ua;
    ua.i.x = (int)__builtin_amdgcn_perm(__float_as_uint(e0.y), __float_as_uint(e0.x), 0x07060302u);
    ua.i.y = (int)__builtin_amdgcn_perm(__float_as_uint(e0.w), __float_as_uint(e0.z), 0x07060302u);
#else
    const f32x4 e0 = *(const f32x4*)(ep);
    const f32x4 e1 = *(const f32x4*)(ep + 4);
    PackA8 ua;
    ua.i.x = (int)__builtin_amdgcn_perm(__float_as_uint(e0.y), __float_as_uint(e0.x), 0x07060302u);
    ua.i.y = (int)__builtin_amdgcn_perm(__float_as_uint(e0.w), __float_as_uint(e0.z), 0x07060302u);
    ua.i.z = (int)__builtin_amdgcn_perm(__float_as_uint(e1.y), __float_as_uint(e1.x), 0x07060302u);
    ua.i.w = (int)__builtin_amdgcn_perm(__float_as_uint(e1.w), __float_as_uint(e1.z), 0x07060302u);
#endif
    V4 av; av.v = *(const f32x4*)ap;

    #pragma unroll
    for (int c = 0; c < 4; ++c) {
      const float m2v = m2p[c*16];
      f32x4 cin;
      cin.x = m1f[c].x + m2v;
      cin.y = m1f[c].y + m2v;
      cin.z = m1f[c].z + m2v;
      cin.w = m1f[c].w + m2v;
#if HAVE_MFMA16
      f32x4 r = __builtin_amdgcn_mfma_f32_16x16x16bf16_1k(ua.h, bfr[c], cin, 0, 0, 0);
#else
      f32x4 r = __builtin_amdgcn_mfma_f32_16x16x32_bf16(ua.h, bfr[c], cin, 0, 0, 0);
#endif
      r.x = fmaxf(r.x, 0.f);
      r.y = fmaxf(r.y, 0.f);
      r.z = fmaxf(r.z, 0.f);
      r.w = fmaxf(r.w, 0.f);
      V4 rv; rv.v = r;
      S2[c][0] = pk_fma(av.h[0], rv.h[0], S2[c][0]);
      S2[c][1] = pk_fma(av.h[1], rv.h[1], S2[c][1]);
    }
    dg0 = pk_add2(dg0, av.h[0]);
    dg1 = pk_add2(dg1, av.h[1]);
    ep  += N_ * CE_;
    ap  += N_;
    m2p += 64;
  }

  // block reduction across the 4 waves (same (b,jt), different i-chunks)
  // row stride 68 floats: quad stride 272 % 32 = 16 -> 2-way bank aliasing (free)
  __shared__ float red[4][16*68];
  __shared__ float redd[4][16];
  #pragma unroll
  for (int c = 0; c < 4; ++c) {
    red[wid][(quad*4 + 0)*68 + c*16 + col] = S2[c][0].x;
    red[wid][(quad*4 + 1)*68 + c*16 + col] = S2[c][0].y;
    red[wid][(quad*4 + 2)*68 + c*16 + col] = S2[c][1].x;
    red[wid][(quad*4 + 3)*68 + c*16 + col] = S2[c][1].y;
  }
  if (col == 0) {
    redd[wid][quad*4 + 0] = dg0.x;
    redd[wid][quad*4 + 1] = dg0.y;
    redd[wid][quad*4 + 2] = dg1.x;
    redd[wid][quad*4 + 3] = dg1.y;
  }
  __syncthreads();

  float* oS = pS + ((size_t)q*BN_ + b*N_ + j0)*64;
  #pragma unroll
  for (int t = 0; t < 4; ++t) {
    const int idx = t*256 + tid;
    const int row = idx >> 6, ch = idx & 63;
    oS[idx] = red[0][row*68 + ch] + red[1][row*68 + ch]
            + red[2][row*68 + ch] + red[3][row*68 + ch];
  }
  if (tid < 16) {
    pdeg[(size_t)q*BN_ + b*N_ + j0 + tid] =
      redd[0][tid] + redd[1][tid] + redd[2][tid] + redd[3][tid];
  }
}

// ---------------- K3: combine partials + fused projection ----------------
__global__ __launch_bounds__(256) void k3_out(
    const float* __restrict__ pS, const float* __restrict__ pdeg,
    const float* __restrict__ base, const float* __restrict__ Wc,
    const float* __restrict__ bc, float* __restrict__ out)
{
  const int tid = threadIdx.x;
  const int r   = tid >> 6;
  const int k   = tid & 63;
  const int row = blockIdx.x*4 + r;
  __shared__ float sm[4][64];
  float s = 0.f, dr = 0.f;
  #pragma unroll
  for (int q = 0; q < Q_; ++q) {
    s  += pS[((size_t)q*BN_ + row)*64 + k];
    dr += pdeg[(size_t)q*BN_ + row];
  }
  sm[r][k] = s;
  __syncthreads();
  float acc = base[(size_t)row*64 + k] + dr * bc[k];
  const float* wr  = Wc + k*64;
  const float* smr = sm[r];
  #pragma unroll
  for (int m = 0; m < 64; ++m) acc += smr[m] * wr[m];
  out[(size_t)row*64 + k] = acc;
}

// ---------------- launch ----------------
extern "C" void kernel_launch(void* const* d_in, const int* in_sizes, int n_in,
                              void* d_out, int out_size, void* d_ws, size_t ws_size,
                              hipStream_t stream)
{
  const float* x    = (const float*)d_in[0];
  const float* adj  = (const float*)d_in[1];
  const float* edge = (const float*)d_in[2];
  const float* W1   = (const float*)d_in[3];
  const float* b1   = (const float*)d_in[4];
  const float* W2   = (const float*)d_in[5];
  const float* b2   = (const float*)d_in[6];
  const float* We   = (const float*)d_in[7];
  const float* be   = (const float*)d_in[8];
  const float* Wn   = (const float*)d_in[9];
  const float* bn   = (const float*)d_in[10];
  const float* Wo1  = (const float*)d_in[11];
  const float* bo1  = (const float*)d_in[12];
  const float* Wo2  = (const float*)d_in[13];
  const float* bo2  = (const float*)d_in[14];
  float* out = (float*)d_out;

  char* ws = (char*)d_ws;
  float* m1   = (float*)(ws);                                  // 1 MiB
  float* m2   = (float*)(ws + (size_t)(1u<<20));               // 1 MiB
  float* base = (float*)(ws + (size_t)2*(1u<<20));             // 1 MiB
  float* Wc   = (float*)(ws + (size_t)3*(1u<<20));             // 16 KiB
  float* bc   = (float*)(ws + (size_t)3*(1u<<20) + 16384);     // 256 B (padded)
  float* pdeg = (float*)(ws + (size_t)3*(1u<<20) + 17408);     // Q*BN*4 = 128 KiB
  float* pS   = (float*)(ws + (size_t)3*(1u<<20) + 17408 + 131072); // Q*BN*64*4 = 8 MiB
  unsigned* wePack = (unsigned*)(ws + (size_t)3*(1u<<20) + 17408 + 131072
                                 + (size_t)Q_*BN_*64*4);       // 4 KiB
  // total ~11.7 MiB of d_ws

  k1_pre<<<BN_/4 + 4, 256, 0, stream>>>(x, W1, b1, W2, b2, Wn, bn,
                                        Wo1, bo1, Wo2, bo2, We,
                                        m1, m2, base, Wc, bc, wePack);
  k2_main<<<2048, 256, 0, stream>>>(edge, adj, wePack, be, m1, m2, pS, pdeg);
  k3_out<<<BN_/4, 256, 0, stream>>>(pS, pdeg, base, Wc, bc, out);
}

// Round 2
// 269.190 us; speedup vs baseline: 1.1088x; 1.0056x over previous
//
#include <hip/hip_runtime.h>
#include <stdint.h>

#define B_   8
#define N_   512
#define CE_  16
#define BN_  (B_*N_)   // 4096
#define Q_   8         // i-partition partials (8 blocks/CU for latency hiding)

typedef __attribute__((ext_vector_type(8))) short bf16x8;
typedef __attribute__((ext_vector_type(4))) short bf16x4;
typedef __attribute__((ext_vector_type(4))) float f32x4;
typedef __attribute__((ext_vector_type(2))) float f32x2;
typedef __attribute__((ext_vector_type(4))) int   i32x4;
typedef __attribute__((ext_vector_type(2))) int   i32x2;

// exact-K MFMA (K=16, no padded half) if the legacy 1k builtin exists on this
// toolchain; otherwise fall back to the verified 16x16x32 zero-padded path.
#if defined(__has_builtin)
#  if __has_builtin(__builtin_amdgcn_mfma_f32_16x16x16bf16_1k)
#    define HAVE_MFMA16 1
#  endif
#endif
#ifndef HAVE_MFMA16
#  define HAVE_MFMA16 0
#endif

union PackA8 { i32x4 i; bf16x8 h; };
union PackA4 { i32x2 i; bf16x4 h; };
union V4     { f32x4 v; f32x2 h[2]; };

__device__ __forceinline__ unsigned short f2bf_rne(float f) {
  unsigned u = __float_as_uint(f);
  u += 0x7FFFu + ((u >> 16) & 1u);
  return (unsigned short)(u >> 16);
}

// packed fp32 (VOP3P, CDNA2+): 2 scalar ops per instruction slot
__device__ __forceinline__ f32x2 pk_fma(f32x2 a, f32x2 b, f32x2 c) {
  f32x2 d;
  asm("v_pk_fma_f32 %0, %1, %2, %3" : "=v"(d) : "v"(a), "v"(b), "v"(c));
  return d;
}
__device__ __forceinline__ f32x2 pk_add2(f32x2 a, f32x2 b) {
  f32x2 d;
  asm("v_pk_add_f32 %0, %1, %2" : "=v"(d) : "v"(a), "v"(b));
  return d;
}

// ---------------- K1: row precompute (m1, m2t, base) + Wc/bc + WeT pack ----------------
// m2 is written TRANSPOSED within each row: m2t[row*64 + col*4 + c] where the
// mid channel = c*16+col -- so k2 reads its 4 per-c values as ONE dwordx4.
__global__ __launch_bounds__(256) void k1_pre(
    const float* __restrict__ x,
    const float* __restrict__ W1,  const float* __restrict__ b1,
    const float* __restrict__ W2,  const float* __restrict__ b2,
    const float* __restrict__ Wn,  const float* __restrict__ bn,
    const float* __restrict__ Wo1, const float* __restrict__ bo1,
    const float* __restrict__ Wo2, const float* __restrict__ bo2,
    const float* __restrict__ We,
    float* __restrict__ m1, float* __restrict__ m2t, float* __restrict__ base,
    float* __restrict__ Wc, float* __restrict__ bc, unsigned* __restrict__ wePack)
{
  const int tid = threadIdx.x;
  const int bx  = blockIdx.x;
  if (bx >= BN_/4) {            // 4 tail blocks: Wc = Wo2@Wn split 16 rows each
    const int q4 = bx - BN_/4;
    for (int idx = tid; idx < 16*64; idx += 256) {
      const int k = q4*16 + (idx >> 6), m = idx & 63;
      float acc = 0.f;
      #pragma unroll 8
      for (int t = 0; t < 64; ++t) acc += Wo2[k*64 + t] * Wn[t*64 + m];
      Wc[k*64 + m] = acc;
    }
    if (q4 == 0) {
      if (tid < 64) {
        float acc = 0.f;
        for (int t = 0; t < 64; ++t) acc += Wo2[tid*64 + t] * bn[t];
        bc[tid] = acc;
      }
      // pre-pack We^T into the exact per-lane MFMA B-fragment layout
      const int c = tid >> 6, lane = tid & 63, col = lane & 15, quad = lane >> 4;
#if HAVE_MFMA16
      const float* wr = We + (c*16 + col)*CE_ + quad*4;
      wePack[tid*2+0] = ((unsigned)f2bf_rne(wr[1]) << 16) | f2bf_rne(wr[0]);
      wePack[tid*2+1] = ((unsigned)f2bf_rne(wr[3]) << 16) | f2bf_rne(wr[2]);
#else
      unsigned p0=0, p1=0, p2=0, p3=0;
      if (quad < 2) {           // B rows k>=16 stay ZERO (garbage-A trick)
        const float* wr = We + (c*16 + col)*CE_ + quad*8;
        p0 = ((unsigned)f2bf_rne(wr[1]) << 16) | f2bf_rne(wr[0]);
        p1 = ((unsigned)f2bf_rne(wr[3]) << 16) | f2bf_rne(wr[2]);
        p2 = ((unsigned)f2bf_rne(wr[5]) << 16) | f2bf_rne(wr[4]);
        p3 = ((unsigned)f2bf_rne(wr[7]) << 16) | f2bf_rne(wr[6]);
      }
      wePack[tid*4+0]=p0; wePack[tid*4+1]=p1; wePack[tid*4+2]=p2; wePack[tid*4+3]=p3;
#endif
    }
    return;
  }
  const int r = tid >> 6, m = tid & 63;
  const int row = bx*4 + r;
  __shared__ float xs[4][64];
  xs[r][m] = x[(size_t)row*64 + m];
  __syncthreads();
  const float* xr = xs[r];
  float a1 = b1[m], a2 = b2[m], a3 = bo1[m] + bo2[m];
  const float* w1r = W1  + m*64;
  const float* w2r = W2  + m*64;
  const float* w3r = Wo1 + m*64;
  #pragma unroll 8
  for (int c = 0; c < 64; ++c) {
    const float xv = xr[c];
    a1 += xv * w1r[c];
    a2 += xv * w2r[c];
    a3 += xv * w3r[c];
  }
  m1[(size_t)row*64 + m]                       = a1;
  m2t[(size_t)row*64 + (m & 15)*4 + (m >> 4)]  = a2;   // transposed-in-row
  base[(size_t)row*64 + m]                     = a3;
}

// ---------------- K2: dense edge projection + relu + masked i-reduction ----------------
// block = 4 waves; block <-> (b, j-tile of 16, i-eighth); wave covers 16 i's.
// Grid remap for XCD affinity: q = blk>>8, grp = blk&255, so all 8 q-partials
// of one grp share blk%8 (= grp%8) -> SAME XCD L2 -> k3's pS reads are L2 hits.
// Edge/adj are read-once streams: nontemporal loads keep them from evicting
// the pS/m1/m2 working set out of L2.
// A[m=lane&15][k=quad*KW+j], C/D: col=lane&15, row=quad*4+reg (verified).
__global__ __launch_bounds__(256) void k2_main(
    const float* __restrict__ edge, const float* __restrict__ adj,
    const unsigned* __restrict__ wePack, const float* __restrict__ be,
    const float* __restrict__ m1,   const float* __restrict__ m2t,
    float* __restrict__ pS, float* __restrict__ pdeg)
{
  const int tid  = threadIdx.x;
  const int lane = tid & 63;
  const int wid  = tid >> 6;
  const int col  = lane & 15;
  const int quad = lane >> 4;

  const int blk = blockIdx.x;       // 0..2047
  const int q   = blk >> 8;         // i-eighth  (XCD-affine: blk%8 == grp%8)
  const int grp = blk & 255;        // 0..255
  const int b   = grp >> 5;
  const int j0  = (grp & 31) << 4;
  const int i0  = q*64 + wid*16;

  // B fragments: one vector load per c from the pre-packed layout
#if HAVE_MFMA16
  bf16x4 bfr[4];
  { const i32x2* wp = (const i32x2*)wePack;
    #pragma unroll
    for (int c = 0; c < 4; ++c) { PackA4 u; u.i = wp[c*64 + lane]; bfr[c] = u.h; } }
#else
  bf16x8 bfr[4];
  { const i32x4* wp = (const i32x4*)wePack;
    #pragma unroll
    for (int c = 0; c < 4; ++c) { PackA8 u; u.i = wp[c*64 + lane]; bfr[c] = u.h; } }
#endif

  // m1 fragment (+be), laid out to match C rows j0+quad*4+reg
  f32x4 m1f[4];
  #pragma unroll
  for (int c = 0; c < 4; ++c) {
    const float bev = be[c*16 + col];
    const float* mp = m1 + (size_t)(b*N_ + j0 + quad*4)*64 + c*16 + col;
    m1f[c].x = mp[0]   + bev;
    m1f[c].y = mp[64]  + bev;
    m1f[c].z = mp[128] + bev;
    m1f[c].w = mp[192] + bev;
  }

  const f32x2 z2 = {0.f, 0.f};
  f32x2 S2[4][2];
  #pragma unroll
  for (int c = 0; c < 4; ++c) { S2[c][0] = z2; S2[c][1] = z2; }
  f32x2 dg0 = z2, dg1 = z2;

#if HAVE_MFMA16
  const float* ep = edge + ((size_t)(b*N_ + i0)*N_ + (j0 + col))*CE_ + quad*4;
#else
  const float* ep = edge + ((size_t)(b*N_ + i0)*N_ + (j0 + col))*CE_ + (quad & 1)*8;
#endif
  const float* ap  = adj + (size_t)(b*N_ + i0)*N_ + j0 + quad*4;
  const float* m2p = m2t + (size_t)(b*N_ + i0)*64 + col*4;

  for (int it = 0; it < 16; ++it) {
#if HAVE_MFMA16
    const f32x4 e0 = __builtin_nontemporal_load((const f32x4*)ep);
    PackA4 ua;
    ua.i.x = (int)__builtin_amdgcn_perm(__float_as_uint(e0.y), __float_as_uint(e0.x), 0x07060302u);
    ua.i.y = (int)__builtin_amdgcn_perm(__float_as_uint(e0.w), __float_as_uint(e0.z), 0x07060302u);
#else
    const f32x4 e0 = __builtin_nontemporal_load((const f32x4*)(ep));
    const f32x4 e1 = __builtin_nontemporal_load((const f32x4*)(ep + 4));
    PackA8 ua;
    ua.i.x = (int)__builtin_amdgcn_perm(__float_as_uint(e0.y), __float_as_uint(e0.x), 0x07060302u);
    ua.i.y = (int)__builtin_amdgcn_perm(__float_as_uint(e0.w), __float_as_uint(e0.z), 0x07060302u);
    ua.i.z = (int)__builtin_amdgcn_perm(__float_as_uint(e1.y), __float_as_uint(e1.x), 0x07060302u);
    ua.i.w = (int)__builtin_amdgcn_perm(__float_as_uint(e1.w), __float_as_uint(e1.z), 0x07060302u);
#endif
    V4 av; av.v = __builtin_nontemporal_load((const f32x4*)ap);
    const f32x4 m2q = *(const f32x4*)m2p;   // 4 per-c values, one dwordx4 (L2-hot)

    #pragma unroll
    for (int c = 0; c < 4; ++c) {
      const float m2v = (c == 0) ? m2q.x : (c == 1) ? m2q.y : (c == 2) ? m2q.z : m2q.w;
      f32x4 cin;
      cin.x = m1f[c].x + m2v;
      cin.y = m1f[c].y + m2v;
      cin.z = m1f[c].z + m2v;
      cin.w = m1f[c].w + m2v;
#if HAVE_MFMA16
      f32x4 r = __builtin_amdgcn_mfma_f32_16x16x16bf16_1k(ua.h, bfr[c], cin, 0, 0, 0);
#else
      f32x4 r = __builtin_amdgcn_mfma_f32_16x16x32_bf16(ua.h, bfr[c], cin, 0, 0, 0);
#endif
      r.x = fmaxf(r.x, 0.f);
      r.y = fmaxf(r.y, 0.f);
      r.z = fmaxf(r.z, 0.f);
      r.w = fmaxf(r.w, 0.f);
      V4 rv; rv.v = r;
      S2[c][0] = pk_fma(av.h[0], rv.h[0], S2[c][0]);
      S2[c][1] = pk_fma(av.h[1], rv.h[1], S2[c][1]);
    }
    dg0 = pk_add2(dg0, av.h[0]);
    dg1 = pk_add2(dg1, av.h[1]);
    ep  += N_ * CE_;
    ap  += N_;
    m2p += 64;
  }

  // block reduction across the 4 waves (same (b,jt), different i-chunks)
  // row stride 68 floats: quad stride 272 % 32 = 16 -> 2-way bank aliasing (free)
  __shared__ float red[4][16*68];
  __shared__ float redd[4][16];
  #pragma unroll
  for (int c = 0; c < 4; ++c) {
    red[wid][(quad*4 + 0)*68 + c*16 + col] = S2[c][0].x;
    red[wid][(quad*4 + 1)*68 + c*16 + col] = S2[c][0].y;
    red[wid][(quad*4 + 2)*68 + c*16 + col] = S2[c][1].x;
    red[wid][(quad*4 + 3)*68 + c*16 + col] = S2[c][1].y;
  }
  if (col == 0) {
    redd[wid][quad*4 + 0] = dg0.x;
    redd[wid][quad*4 + 1] = dg0.y;
    redd[wid][quad*4 + 2] = dg1.x;
    redd[wid][quad*4 + 3] = dg1.y;
  }
  __syncthreads();

  float* oS = pS + ((size_t)q*BN_ + b*N_ + j0)*64;
  #pragma unroll
  for (int t = 0; t < 4; ++t) {
    const int idx = t*256 + tid;
    const int row = idx >> 6, ch = idx & 63;
    oS[idx] = red[0][row*68 + ch] + red[1][row*68 + ch]
            + red[2][row*68 + ch] + red[3][row*68 + ch];
  }
  if (tid < 16) {
    pdeg[(size_t)q*BN_ + b*N_ + j0 + tid] =
      redd[0][tid] + redd[1][tid] + redd[2][tid] + redd[3][tid];
  }
}

// ---------------- K3: combine partials + fused projection ----------------
// Row mapping matched to k2's XCD grouping: this block's XCD (bid%8) equals
// grp%8 of the rows it reduces, so the 8 pS partials are in the local L2.
__global__ __launch_bounds__(256) void k3_out(
    const float* __restrict__ pS, const float* __restrict__ pdeg,
    const float* __restrict__ base, const float* __restrict__ Wc,
    const float* __restrict__ bc, float* __restrict__ out)
{
  const int tid = threadIdx.x;
  const int r   = tid >> 6;
  const int k   = tid & 63;
  const int bid = blockIdx.x;           // 0..1023
  const int x8  = bid & 7;
  const int u   = bid >> 3;             // 0..127
  const int g   = x8 + 8*(u >> 2);      // grp 0..255, g%8 == bid%8
  const int row = g*16 + (u & 3)*4 + r;
  __shared__ float sm[4][64];
  float s = 0.f, dr = 0.f;
  #pragma unroll
  for (int q = 0; q < Q_; ++q) {
    s  += pS[((size_t)q*BN_ + row)*64 + k];
    dr += pdeg[(size_t)q*BN_ + row];
  }
  sm[r][k] = s;
  __syncthreads();
  float acc = base[(size_t)row*64 + k] + dr * bc[k];
  const float* wr  = Wc + k*64;
  const float* smr = sm[r];
  #pragma unroll
  for (int m = 0; m < 64; ++m) acc += smr[m] * wr[m];
  out[(size_t)row*64 + k] = acc;
}

// ---------------- launch ----------------
extern "C" void kernel_launch(void* const* d_in, const int* in_sizes, int n_in,
                              void* d_out, int out_size, void* d_ws, size_t ws_size,
                              hipStream_t stream)
{
  const float* x    = (const float*)d_in[0];
  const float* adj  = (const float*)d_in[1];
  const float* edge = (const float*)d_in[2];
  const float* W1   = (const float*)d_in[3];
  const float* b1   = (const float*)d_in[4];
  const float* W2   = (const float*)d_in[5];
  const float* b2   = (const float*)d_in[6];
  const float* We   = (const float*)d_in[7];
  const float* be   = (const float*)d_in[8];
  const float* Wn   = (const float*)d_in[9];
  const float* bn   = (const float*)d_in[10];
  const float* Wo1  = (const float*)d_in[11];
  const float* bo1  = (const float*)d_in[12];
  const float* Wo2  = (const float*)d_in[13];
  const float* bo2  = (const float*)d_in[14];
  float* out = (float*)d_out;

  char* ws = (char*)d_ws;
  float* m1   = (float*)(ws);                                  // 1 MiB
  float* m2t  = (float*)(ws + (size_t)(1u<<20));               // 1 MiB (transposed)
  float* base = (float*)(ws + (size_t)2*(1u<<20));             // 1 MiB
  float* Wc   = (float*)(ws + (size_t)3*(1u<<20));             // 16 KiB
  float* bc   = (float*)(ws + (size_t)3*(1u<<20) + 16384);     // 256 B (padded)
  float* pdeg = (float*)(ws + (size_t)3*(1u<<20) + 17408);     // Q*BN*4 = 128 KiB
  float* pS   = (float*)(ws + (size_t)3*(1u<<20) + 17408 + 131072); // Q*BN*64*4 = 8 MiB
  unsigned* wePack = (unsigned*)(ws + (size_t)3*(1u<<20) + 17408 + 131072
                                 + (size_t)Q_*BN_*64*4);       // 4 KiB
  // total ~11.7 MiB of d_ws

  k1_pre<<<BN_/4 + 4, 256, 0, stream>>>(x, W1, b1, W2, b2, Wn, bn,
                                        Wo1, bo1, Wo2, bo2, We,
                                        m1, m2t, base, Wc, bc, wePack);
  k2_main<<<2048, 256, 0, stream>>>(edge, adj, wePack, be, m1, m2t, pS, pdeg);
  k3_out<<<BN_/4, 256, 0, stream>>>(pS, pdeg, base, Wc, bc, out);
}